// Round 1
// baseline (183.183 us; speedup 1.0000x reference)
//
#include <hip/hip_runtime.h>
#include <hip/hip_bf16.h>

// GridToMeshEncoder fused kernel (fp32 baseline).
// grid_data (B, 721, 1440, 64) f32 ; mesh_features (M,4) f32 ;
// indices (M,4) i32 ; weights (M,4) f32 ; W1 (68,256) ; b1 (256) ;
// W2 (256,256) ; b2 (256) ; out (B, M, 256) f32.

constexpr int kNLat  = 721;
constexpr int kNLon  = 1440;
constexpr long long kNPix = (long long)kNLat * kNLon;   // 1038240
constexpr int kMesh  = 40962;
constexpr int kCIn   = 64;
constexpr int kFeat  = 4;
constexpr int kDIn   = kCIn + kFeat;                    // 68
constexpr int kHid   = 256;
constexpr int kOut   = 256;
constexpr int kBatch = 2;

constexpr int MP   = 32;                                // mesh points per block
constexpr int NBLK = (kMesh + MP - 1) / MP;             // 1281

__global__ __launch_bounds__(256)
void g2m_fused(const float* __restrict__ grid,
               const float* __restrict__ mfeat,
               const int*   __restrict__ indices,
               const float* __restrict__ weights,
               const float* __restrict__ W1,
               const float* __restrict__ b1,
               const float* __restrict__ W2,
               const float* __restrict__ b2,
               float* __restrict__ out)
{
    __shared__ float comb[MP][kDIn];    // 32*68*4  = 8704 B
    __shared__ float hbuf[MP][kHid];    // 32*256*4 = 32768 B

    const int t  = threadIdx.x;
    const int b  = blockIdx.y;
    const int m0 = blockIdx.x * MP;

    // ---------------- stage combined features into LDS ----------------
    {
        const int c    = t & 63;        // channel lane
        const int psub = t >> 6;        // wave id: which point this pass
        const float* gb = grid + (size_t)b * (size_t)(kNPix * kCIn);
        #pragma unroll
        for (int pass = 0; pass < MP / 4; ++pass) {
            const int p = pass * 4 + psub;
            const int m = m0 + p;
            float v  = 0.f;
            float mf = 0.f;
            if (m < kMesh) {
                const int4   id = *reinterpret_cast<const int4*>(indices + (size_t)m * 4);
                const float4 w  = *reinterpret_cast<const float4*>(weights + (size_t)m * 4);
                // 4 coalesced 256B row reads (index wave-uniform, lanes span channels)
                v = fmaf(w.x, gb[(size_t)id.x * kCIn + c],
                    fmaf(w.y, gb[(size_t)id.y * kCIn + c],
                    fmaf(w.z, gb[(size_t)id.z * kCIn + c],
                         w.w * gb[(size_t)id.w * kCIn + c])));
                if (c < kFeat) mf = mfeat[(size_t)m * kFeat + c];
            }
            comb[p][c] = v;
            if (c < kFeat) comb[p][kCIn + c] = mf;
        }
    }
    __syncthreads();

    // thread tile: 8 rows (by wave) x 4 cols (by lane)
    const int jg = t & 63;
    const int pg = t >> 6;
    const int j0 = jg * 4;
    const int p0 = pg * 8;

    float acc[8][4];
    #pragma unroll
    for (int i = 0; i < 8; ++i)
        #pragma unroll
        for (int j = 0; j < 4; ++j) acc[i][j] = 0.f;

    // ---------------- part 1: h = relu(comb @ W1 + b1) ----------------
    for (int c = 0; c < kDIn; c += 4) {
        float4 wrow[4];
        #pragma unroll
        for (int k = 0; k < 4; ++k)
            wrow[k] = *reinterpret_cast<const float4*>(W1 + (size_t)(c + k) * kHid + j0);
        #pragma unroll
        for (int pp = 0; pp < 8; ++pp) {
            const float4 a = *reinterpret_cast<const float4*>(&comb[p0 + pp][c]);
            const float av[4] = {a.x, a.y, a.z, a.w};
            #pragma unroll
            for (int k = 0; k < 4; ++k) {
                acc[pp][0] = fmaf(av[k], wrow[k].x, acc[pp][0]);
                acc[pp][1] = fmaf(av[k], wrow[k].y, acc[pp][1]);
                acc[pp][2] = fmaf(av[k], wrow[k].z, acc[pp][2]);
                acc[pp][3] = fmaf(av[k], wrow[k].w, acc[pp][3]);
            }
        }
    }

    {
        const float4 bv = *reinterpret_cast<const float4*>(b1 + j0);
        #pragma unroll
        for (int pp = 0; pp < 8; ++pp) {
            float4 h;
            h.x = fmaxf(acc[pp][0] + bv.x, 0.f);
            h.y = fmaxf(acc[pp][1] + bv.y, 0.f);
            h.z = fmaxf(acc[pp][2] + bv.z, 0.f);
            h.w = fmaxf(acc[pp][3] + bv.w, 0.f);
            *reinterpret_cast<float4*>(&hbuf[p0 + pp][j0]) = h;
        }
    }
    __syncthreads();

    #pragma unroll
    for (int i = 0; i < 8; ++i)
        #pragma unroll
        for (int j = 0; j < 4; ++j) acc[i][j] = 0.f;

    // ---------------- part 2: out = h @ W2 + b2 ----------------
    for (int c = 0; c < kHid; c += 4) {
        float4 wrow[4];
        #pragma unroll
        for (int k = 0; k < 4; ++k)
            wrow[k] = *reinterpret_cast<const float4*>(W2 + (size_t)(c + k) * kOut + j0);
        #pragma unroll
        for (int pp = 0; pp < 8; ++pp) {
            const float4 a = *reinterpret_cast<const float4*>(&hbuf[p0 + pp][c]);
            const float av[4] = {a.x, a.y, a.z, a.w};
            #pragma unroll
            for (int k = 0; k < 4; ++k) {
                acc[pp][0] = fmaf(av[k], wrow[k].x, acc[pp][0]);
                acc[pp][1] = fmaf(av[k], wrow[k].y, acc[pp][1]);
                acc[pp][2] = fmaf(av[k], wrow[k].z, acc[pp][2]);
                acc[pp][3] = fmaf(av[k], wrow[k].w, acc[pp][3]);
            }
        }
    }

    {
        const float4 bv = *reinterpret_cast<const float4*>(b2 + j0);
        #pragma unroll
        for (int pp = 0; pp < 8; ++pp) {
            const int m = m0 + p0 + pp;
            if (m < kMesh) {
                float4 o;
                o.x = acc[pp][0] + bv.x;
                o.y = acc[pp][1] + bv.y;
                o.z = acc[pp][2] + bv.z;
                o.w = acc[pp][3] + bv.w;
                *reinterpret_cast<float4*>(out + ((size_t)b * kMesh + m) * (size_t)kOut + j0) = o;
            }
        }
    }
}

extern "C" void kernel_launch(void* const* d_in, const int* in_sizes, int n_in,
                              void* d_out, int out_size, void* d_ws, size_t ws_size,
                              hipStream_t stream) {
    const float* grid    = (const float*)d_in[0];
    const float* mfeat   = (const float*)d_in[1];
    const int*   indices = (const int*)d_in[2];
    const float* weights = (const float*)d_in[3];
    const float* W1      = (const float*)d_in[4];
    const float* b1      = (const float*)d_in[5];
    const float* W2      = (const float*)d_in[6];
    const float* b2      = (const float*)d_in[7];
    float* o = (float*)d_out;

    dim3 grd(NBLK, kBatch);
    g2m_fused<<<grd, 256, 0, stream>>>(grid, mfeat, indices, weights, W1, b1, W2, b2, o);
}

// Round 2
// 85.495 us; speedup vs baseline: 2.1426x; 2.1426x over previous
//
#include <hip/hip_runtime.h>
#include <hip/hip_bf16.h>

// GridToMeshEncoder: gather+bilinear -> concat -> MLP(68->256 relu ->256)
// R2: bf16 MFMA path. W1/W2 pre-packed to fragment-ordered bf16 in d_ws by a
// prep kernel; main kernel: interp -> GEMM1 (transposed, h^T=W1^T*comb^T) ->
// GEMM2 (out = h*W2). Fallback to fp32 kernel if ws too small.

constexpr int kNLat  = 721;
constexpr int kNLon  = 1440;
constexpr long long kNPix = (long long)kNLat * kNLon;   // 1038240
constexpr int kMesh  = 40962;
constexpr int kCIn   = 64;
constexpr int kFeat  = 4;
constexpr int kDIn   = kCIn + kFeat;                    // 68
constexpr int kHid   = 256;
constexpr int kOut   = 256;
constexpr int kBatch = 2;

typedef __attribute__((ext_vector_type(8))) short bf16x8;
typedef __attribute__((ext_vector_type(4))) float f32x4;

// ---------------- MFMA kernel geometry ----------------
constexpr int MP   = 64;                     // mesh points per block
constexpr int NBLK = (kMesh + MP - 1) / MP;  // 641
constexpr int CSTR = 104;  // comb row stride (bf16): 68 data + pad to 96 K + bank stagger
constexpr int HSTR = 264;  // hbuf row stride (bf16): 256 data + 8 pad

// ws layout (ushort units): wsA1 = W1^T A-frags [rt:16][ks:3][lane:64][j:8]
//                           wsB2 = W2  B-frags  [ct:16][ks:8][lane:64][j:8]
constexpr int WSA1_N = 16 * 3 * 64 * 8;      // 24576
constexpr int WSB2_N = 16 * 8 * 64 * 8;      // 65536
constexpr size_t WS_BYTES = (size_t)(WSA1_N + WSB2_N) * 2;  // 180224

__device__ inline ushort f2b(float v) {
    __hip_bfloat16 h = __float2bfloat16(v);
    return *reinterpret_cast<ushort*>(&h);
}

// ---------------- prep: pack W1/W2 into frag-ordered bf16 ----------------
__global__ __launch_bounds__(256)
void g2m_prep(const float* __restrict__ W1, const float* __restrict__ W2,
              ushort* __restrict__ ws) {
    const int tid = blockIdx.x * 256 + threadIdx.x;
    if (tid < 3072) {                       // wsA1: A[i=hid][k] = W1[k][hid]
        const int l  = tid & 63;
        const int g  = tid >> 6;            // g = rt*3 + ks
        const int ks = g % 3;
        const int rt = g / 3;
        const int hid = rt * 16 + (l & 15);
        const int k0  = ks * 32 + (l >> 4) * 8;
        ushort tmp[8];
        #pragma unroll
        for (int j = 0; j < 8; ++j) {
            const int k = k0 + j;
            tmp[j] = f2b(k < kDIn ? W1[(size_t)k * kHid + hid] : 0.f);
        }
        *reinterpret_cast<bf16x8*>(ws + (size_t)tid * 8) =
            *reinterpret_cast<bf16x8*>(tmp);
    } else if (tid < 11264) {               // wsB2: B[k][j=col] = W2[k][col]
        const int q  = tid - 3072;
        const int l  = q & 63;
        const int g  = q >> 6;              // g = ct*8 + ks
        const int ks = g % 8;
        const int ct = g / 8;
        const int col = ct * 16 + (l & 15);
        const int k0  = ks * 32 + (l >> 4) * 8;
        ushort tmp[8];
        #pragma unroll
        for (int j = 0; j < 8; ++j) {
            const int k = k0 + j;
            tmp[j] = f2b(W2[(size_t)k * kOut + col]);
        }
        *reinterpret_cast<bf16x8*>(ws + (size_t)(WSA1_N + q * 8)) =
            *reinterpret_cast<bf16x8*>(tmp);
    }
}

// ---------------- main fused MFMA kernel ----------------
__global__ __launch_bounds__(256)
void g2m_mfma(const float* __restrict__ grid,
              const float* __restrict__ mfeat,
              const int*   __restrict__ indices,
              const float* __restrict__ weights,
              const float* __restrict__ b1,
              const float* __restrict__ b2,
              const ushort* __restrict__ ws,
              float* __restrict__ out)
{
    __shared__ __align__(16) ushort comb[MP * CSTR];   // 13312 B
    __shared__ __align__(16) ushort hbuf[MP * HSTR];   // 33792 B

    const int t    = threadIdx.x;
    const int lane = t & 63;
    const int w    = t >> 6;        // wave id 0..3
    const int b    = blockIdx.y;
    const int m0   = blockIdx.x * MP;
    const int l15  = lane & 15;
    const int l4   = lane >> 4;

    // ---- phase 1: gather + bilinear interp -> comb[m][k] (bf16) ----
    {
        const int c = lane;                            // channel
        const float* gb = grid + (size_t)b * (size_t)(kNPix * kCIn);
        #pragma unroll 4
        for (int pass = 0; pass < MP / 4; ++pass) {
            const int p = pass * 4 + w;
            const int m = m0 + p;
            float v = 0.f, mf = 0.f;
            if (m < kMesh) {
                const int4   id = *reinterpret_cast<const int4*>(indices + (size_t)m * 4);
                const float4 wt = *reinterpret_cast<const float4*>(weights + (size_t)m * 4);
                v = fmaf(wt.x, gb[(size_t)id.x * kCIn + c],
                    fmaf(wt.y, gb[(size_t)id.y * kCIn + c],
                    fmaf(wt.z, gb[(size_t)id.z * kCIn + c],
                         wt.w * gb[(size_t)id.w * kCIn + c])));
                if (c < kFeat) mf = mfeat[(size_t)m * kFeat + c];
            }
            comb[p * CSTR + c] = f2b(v);
            if (c < kFeat) comb[p * CSTR + kCIn + c] = f2b(mf);
            if (c < CSTR - kDIn) comb[p * CSTR + kDIn + c] = 0;  // zero K-pad
        }
    }
    __syncthreads();

    // ---- phase 2: h^T = W1^T @ comb^T  (D rows = hid, cols = mesh) ----
    {
        f32x4 acc1[4][4];                              // [r(hid-tile)][mt(mesh-tile)]
        #pragma unroll
        for (int r = 0; r < 4; ++r)
            #pragma unroll
            for (int mt = 0; mt < 4; ++mt) acc1[r][mt] = (f32x4)0.f;

        #pragma unroll
        for (int ks = 0; ks < 3; ++ks) {
            bf16x8 af[4], bfr[4];
            #pragma unroll
            for (int r = 0; r < 4; ++r) {
                const int rt = w * 4 + r;
                af[r] = *reinterpret_cast<const bf16x8*>(
                            ws + (size_t)((rt * 3 + ks) * 64 + lane) * 8);
            }
            #pragma unroll
            for (int mt = 0; mt < 4; ++mt)
                bfr[mt] = *reinterpret_cast<const bf16x8*>(
                            &comb[(mt * 16 + l15) * CSTR + ks * 32 + l4 * 8]);
            #pragma unroll
            for (int r = 0; r < 4; ++r)
                #pragma unroll
                for (int mt = 0; mt < 4; ++mt)
                    acc1[r][mt] = __builtin_amdgcn_mfma_f32_16x16x32_bf16(
                                      af[r], bfr[mt], acc1[r][mt], 0, 0, 0);
        }

        // bias + relu + store h to LDS transposed back: hbuf[m][hid]
        #pragma unroll
        for (int r = 0; r < 4; ++r) {
            const int hid0 = (w * 4 + r) * 16 + l4 * 4;
            const float4 bv = *reinterpret_cast<const float4*>(b1 + hid0);
            #pragma unroll
            for (int mt = 0; mt < 4; ++mt) {
                const int m = mt * 16 + l15;
                ushort4 hv;
                hv.x = f2b(fmaxf(acc1[r][mt][0] + bv.x, 0.f));
                hv.y = f2b(fmaxf(acc1[r][mt][1] + bv.y, 0.f));
                hv.z = f2b(fmaxf(acc1[r][mt][2] + bv.z, 0.f));
                hv.w = f2b(fmaxf(acc1[r][mt][3] + bv.w, 0.f));
                *reinterpret_cast<ushort4*>(&hbuf[m * HSTR + hid0]) = hv;
            }
        }
    }
    __syncthreads();

    // ---- phase 3: out = h @ W2 + b2 ----
    {
        f32x4 acc2[4][4];                              // [mt(mesh)][c(out-tile)]
        #pragma unroll
        for (int mt = 0; mt < 4; ++mt)
            #pragma unroll
            for (int c = 0; c < 4; ++c) acc2[mt][c] = (f32x4)0.f;

        #pragma unroll
        for (int ks = 0; ks < 8; ++ks) {
            bf16x8 af[4], bfr[4];
            #pragma unroll
            for (int mt = 0; mt < 4; ++mt)
                af[mt] = *reinterpret_cast<const bf16x8*>(
                            &hbuf[(mt * 16 + l15) * HSTR + ks * 32 + l4 * 8]);
            #pragma unroll
            for (int c = 0; c < 4; ++c) {
                const int ct = w * 4 + c;
                bfr[c] = *reinterpret_cast<const bf16x8*>(
                            ws + (size_t)(WSA1_N + ((ct * 8 + ks) * 64 + lane) * 8));
            }
            #pragma unroll
            for (int mt = 0; mt < 4; ++mt)
                #pragma unroll
                for (int c = 0; c < 4; ++c)
                    acc2[mt][c] = __builtin_amdgcn_mfma_f32_16x16x32_bf16(
                                      af[mt], bfr[c], acc2[mt][c], 0, 0, 0);
        }

        // epilogue: out[b][m][col]  (col = ct*16 + l15, rows = mesh)
        #pragma unroll
        for (int c = 0; c < 4; ++c) {
            const int ct  = w * 4 + c;
            const int col = ct * 16 + l15;
            const float bb = b2[col];
            #pragma unroll
            for (int mt = 0; mt < 4; ++mt) {
                const int mloc = mt * 16 + l4 * 4;
                #pragma unroll
                for (int r = 0; r < 4; ++r) {
                    const int m = m0 + mloc + r;
                    if (m < kMesh)
                        out[((size_t)b * kMesh + m) * kOut + col] = acc2[mt][c][r] + bb;
                }
            }
        }
    }
}

// ---------------- fp32 fallback (R1 kernel, proven) ----------------
constexpr int FMP   = 32;
constexpr int FNBLK = (kMesh + FMP - 1) / FMP;

__global__ __launch_bounds__(256)
void g2m_fused(const float* __restrict__ grid,
               const float* __restrict__ mfeat,
               const int*   __restrict__ indices,
               const float* __restrict__ weights,
               const float* __restrict__ W1,
               const float* __restrict__ b1,
               const float* __restrict__ W2,
               const float* __restrict__ b2,
               float* __restrict__ out)
{
    __shared__ float comb[FMP][kDIn];
    __shared__ float hbuf[FMP][kHid];

    const int t  = threadIdx.x;
    const int b  = blockIdx.y;
    const int m0 = blockIdx.x * FMP;

    {
        const int c    = t & 63;
        const int psub = t >> 6;
        const float* gb = grid + (size_t)b * (size_t)(kNPix * kCIn);
        #pragma unroll
        for (int pass = 0; pass < FMP / 4; ++pass) {
            const int p = pass * 4 + psub;
            const int m = m0 + p;
            float v = 0.f, mf = 0.f;
            if (m < kMesh) {
                const int4   id = *reinterpret_cast<const int4*>(indices + (size_t)m * 4);
                const float4 wv = *reinterpret_cast<const float4*>(weights + (size_t)m * 4);
                v = fmaf(wv.x, gb[(size_t)id.x * kCIn + c],
                    fmaf(wv.y, gb[(size_t)id.y * kCIn + c],
                    fmaf(wv.z, gb[(size_t)id.z * kCIn + c],
                         wv.w * gb[(size_t)id.w * kCIn + c])));
                if (c < kFeat) mf = mfeat[(size_t)m * kFeat + c];
            }
            comb[p][c] = v;
            if (c < kFeat) comb[p][kCIn + c] = mf;
        }
    }
    __syncthreads();

    const int jg = t & 63, pg = t >> 6;
    const int j0 = jg * 4, p0 = pg * 8;

    float acc[8][4];
    #pragma unroll
    for (int i = 0; i < 8; ++i)
        #pragma unroll
        for (int j = 0; j < 4; ++j) acc[i][j] = 0.f;

    for (int c = 0; c < kDIn; c += 4) {
        float4 wrow[4];
        #pragma unroll
        for (int k = 0; k < 4; ++k)
            wrow[k] = *reinterpret_cast<const float4*>(W1 + (size_t)(c + k) * kHid + j0);
        #pragma unroll
        for (int pp = 0; pp < 8; ++pp) {
            const float4 a = *reinterpret_cast<const float4*>(&comb[p0 + pp][c]);
            const float av[4] = {a.x, a.y, a.z, a.w};
            #pragma unroll
            for (int k = 0; k < 4; ++k) {
                acc[pp][0] = fmaf(av[k], wrow[k].x, acc[pp][0]);
                acc[pp][1] = fmaf(av[k], wrow[k].y, acc[pp][1]);
                acc[pp][2] = fmaf(av[k], wrow[k].z, acc[pp][2]);
                acc[pp][3] = fmaf(av[k], wrow[k].w, acc[pp][3]);
            }
        }
    }
    {
        const float4 bv = *reinterpret_cast<const float4*>(b1 + j0);
        #pragma unroll
        for (int pp = 0; pp < 8; ++pp) {
            float4 h;
            h.x = fmaxf(acc[pp][0] + bv.x, 0.f);
            h.y = fmaxf(acc[pp][1] + bv.y, 0.f);
            h.z = fmaxf(acc[pp][2] + bv.z, 0.f);
            h.w = fmaxf(acc[pp][3] + bv.w, 0.f);
            *reinterpret_cast<float4*>(&hbuf[p0 + pp][j0]) = h;
        }
    }
    __syncthreads();

    #pragma unroll
    for (int i = 0; i < 8; ++i)
        #pragma unroll
        for (int j = 0; j < 4; ++j) acc[i][j] = 0.f;

    for (int c = 0; c < kHid; c += 4) {
        float4 wrow[4];
        #pragma unroll
        for (int k = 0; k < 4; ++k)
            wrow[k] = *reinterpret_cast<const float4*>(W2 + (size_t)(c + k) * kOut + j0);
        #pragma unroll
        for (int pp = 0; pp < 8; ++pp) {
            const float4 a = *reinterpret_cast<const float4*>(&hbuf[p0 + pp][c]);
            const float av[4] = {a.x, a.y, a.z, a.w};
            #pragma unroll
            for (int k = 0; k < 4; ++k) {
                acc[pp][0] = fmaf(av[k], wrow[k].x, acc[pp][0]);
                acc[pp][1] = fmaf(av[k], wrow[k].y, acc[pp][1]);
                acc[pp][2] = fmaf(av[k], wrow[k].z, acc[pp][2]);
                acc[pp][3] = fmaf(av[k], wrow[k].w, acc[pp][3]);
            }
        }
    }
    {
        const float4 bv = *reinterpret_cast<const float4*>(b2 + j0);
        #pragma unroll
        for (int pp = 0; pp < 8; ++pp) {
            const int m = m0 + p0 + pp;
            if (m < kMesh) {
                float4 o;
                o.x = acc[pp][0] + bv.x;
                o.y = acc[pp][1] + bv.y;
                o.z = acc[pp][2] + bv.z;
                o.w = acc[pp][3] + bv.w;
                *reinterpret_cast<float4*>(out + ((size_t)b * kMesh + m) * (size_t)kOut + j0) = o;
            }
        }
    }
}

extern "C" void kernel_launch(void* const* d_in, const int* in_sizes, int n_in,
                              void* d_out, int out_size, void* d_ws, size_t ws_size,
                              hipStream_t stream) {
    const float* grid    = (const float*)d_in[0];
    const float* mfeat   = (const float*)d_in[1];
    const int*   indices = (const int*)d_in[2];
    const float* weights = (const float*)d_in[3];
    const float* W1      = (const float*)d_in[4];
    const float* b1      = (const float*)d_in[5];
    const float* W2      = (const float*)d_in[6];
    const float* b2      = (const float*)d_in[7];
    float* o = (float*)d_out;

    if (ws_size >= WS_BYTES) {
        ushort* ws = (ushort*)d_ws;
        g2m_prep<<<44, 256, 0, stream>>>(W1, W2, ws);
        dim3 grd(NBLK, kBatch);
        g2m_mfma<<<grd, 256, 0, stream>>>(grid, mfeat, indices, weights, b1, b2, ws, o);
    } else {
        dim3 grd(FNBLK, kBatch);
        g2m_fused<<<grd, 256, 0, stream>>>(grid, mfeat, indices, weights, W1, b1, W2, b2, o);
    }
}

// Round 3
// 62.329 us; speedup vs baseline: 2.9390x; 1.3717x over previous
//
#include <hip/hip_runtime.h>
#include <hip/hip_bf16.h>

// GridToMeshEncoder R3: split into regime-matched kernels.
//   g2m_prep   : pack W1^T / W2 into MFMA-fragment-ordered bf16 (ws)
//   g2m_gather : random-row gather + bilinear interp -> bf16 comb[p][96] (ws)
//   g2m_mlp    : GEMM1 (h^T = W1^T * comb^T, MFMA) -> LDS -> GEMM2 -> out
// Fallback: R2 fused MFMA kernel if ws too small.

constexpr int kNLat  = 721;
constexpr int kNLon  = 1440;
constexpr long long kNPix = (long long)kNLat * kNLon;   // 1038240
constexpr int kMesh  = 40962;
constexpr int kCIn   = 64;
constexpr int kFeat  = 4;
constexpr int kDIn   = kCIn + kFeat;                    // 68
constexpr int kHid   = 256;
constexpr int kOut   = 256;
constexpr int kBatch = 2;

constexpr int kPts    = kBatch * kMesh;                 // 81924
constexpr int kPtsPad = (kPts + 63) & ~63;              // 81984
constexpr int KP      = 96;                             // padded K for comb

typedef __attribute__((ext_vector_type(8))) short bf16x8;
typedef __attribute__((ext_vector_type(4))) float f32x4;

// ws layout (ushort units)
constexpr int    WSA1_N   = 16 * 3 * 64 * 8;            // 24576  (W1^T A-frags)
constexpr int    WSB2_N   = 16 * 8 * 64 * 8;            // 65536  (W2 B-frags)
constexpr size_t COMB_OFF = WSA1_N + WSB2_N;            // 90112 (x2B = 180224, 16B aligned)
constexpr size_t COMB_N   = (size_t)kPtsPad * KP;       // 7,870,464
constexpr size_t WS_SPLIT_BYTES = (COMB_OFF + COMB_N) * 2;   // ~15.9 MB
constexpr size_t WS_FUSED_BYTES = COMB_OFF * 2;              // 180224

__device__ inline ushort f2b(float v) {
    __hip_bfloat16 h = __float2bfloat16(v);
    return *reinterpret_cast<ushort*>(&h);
}

// ---------------- prep: pack W1/W2 into frag-ordered bf16 ----------------
__global__ __launch_bounds__(256)
void g2m_prep(const float* __restrict__ W1, const float* __restrict__ W2,
              ushort* __restrict__ ws) {
    const int tid = blockIdx.x * 256 + threadIdx.x;
    if (tid < 3072) {                       // wsA1: A[i=hid][k] = W1[k][hid]
        const int l  = tid & 63;
        const int g  = tid >> 6;            // g = rt*3 + ks
        const int ks = g % 3;
        const int rt = g / 3;
        const int hid = rt * 16 + (l & 15);
        const int k0  = ks * 32 + (l >> 4) * 8;
        ushort tmp[8];
        #pragma unroll
        for (int j = 0; j < 8; ++j) {
            const int k = k0 + j;
            tmp[j] = f2b(k < kDIn ? W1[(size_t)k * kHid + hid] : 0.f);
        }
        *reinterpret_cast<bf16x8*>(ws + (size_t)tid * 8) =
            *reinterpret_cast<bf16x8*>(tmp);
    } else if (tid < 11264) {               // wsB2: B[k][j=col] = W2[k][col]
        const int q  = tid - 3072;
        const int l  = q & 63;
        const int g  = q >> 6;              // g = ct*8 + ks
        const int ks = g % 8;
        const int ct = g / 8;
        const int col = ct * 16 + (l & 15);
        const int k0  = ks * 32 + (l >> 4) * 8;
        ushort tmp[8];
        #pragma unroll
        for (int j = 0; j < 8; ++j) {
            const int k = k0 + j;
            tmp[j] = f2b(W2[(size_t)k * kOut + col]);
        }
        *reinterpret_cast<bf16x8*>(ws + (size_t)(WSA1_N + q * 8)) =
            *reinterpret_cast<bf16x8*>(tmp);
    }
}

// ---------------- gather: interp -> comb[p][KP] bf16 ----------------
__global__ __launch_bounds__(256)
void g2m_gather(const float* __restrict__ grid,
                const float* __restrict__ mfeat,
                const int*   __restrict__ indices,
                const float* __restrict__ weights,
                ushort* __restrict__ comb) {
    const int lane = threadIdx.x & 63;              // channel
    const int wid  = (blockIdx.x * 256 + threadIdx.x) >> 6;
    const int nw   = (gridDim.x * 256) >> 6;

    for (int p = wid; p < kPtsPad; p += nw) {
        float v = 0.f, mf = 0.f;
        if (p < kPts) {
            const int b = p / kMesh;
            const int m = p - b * kMesh;
            const int4   id = *reinterpret_cast<const int4*>(indices + (size_t)m * 4);
            const float4 wt = *reinterpret_cast<const float4*>(weights + (size_t)m * 4);
            const float* gb = grid + (size_t)b * (size_t)(kNPix * kCIn);
            v = fmaf(wt.x, gb[(size_t)id.x * kCIn + lane],
                fmaf(wt.y, gb[(size_t)id.y * kCIn + lane],
                fmaf(wt.z, gb[(size_t)id.z * kCIn + lane],
                     wt.w * gb[(size_t)id.w * kCIn + lane])));
            if (lane < kFeat) mf = mfeat[(size_t)m * kFeat + lane];
        }
        ushort* row = comb + (size_t)p * KP;
        row[lane] = f2b(v);
        if (lane < kFeat) row[kCIn + lane] = f2b(mf);
        if (lane < KP - kDIn) row[kDIn + lane] = 0;     // zero K-pad (28)
    }
}

// ---------------- MLP: GEMM1 -> LDS -> GEMM2 -> out ----------------
constexpr int MP    = 64;                       // points per block
constexpr int NBLKB = kPtsPad / MP;             // 1281
constexpr int HSTR  = 264;                      // hbuf row stride (bf16)

__global__ __launch_bounds__(256)
void g2m_mlp(const ushort* __restrict__ comb,
             const float* __restrict__ b1,
             const float* __restrict__ b2,
             const ushort* __restrict__ ws,
             float* __restrict__ out)
{
    __shared__ __align__(16) ushort hbuf[MP * HSTR];    // 33792 B

    const int t    = threadIdx.x;
    const int lane = t & 63;
    const int w    = t >> 6;                    // wave id 0..3
    const int p0   = blockIdx.x * MP;
    const int l15  = lane & 15;
    const int l4   = lane >> 4;

    // ---- GEMM1: h^T = W1^T @ comb^T ----
    {
        f32x4 acc1[4][4];                       // [r(hid-tile)][mt(pt-tile)]
        #pragma unroll
        for (int r = 0; r < 4; ++r)
            #pragma unroll
            for (int mt = 0; mt < 4; ++mt) acc1[r][mt] = (f32x4)0.f;

        #pragma unroll
        for (int ks = 0; ks < 3; ++ks) {
            bf16x8 af[4], bfr[4];
            #pragma unroll
            for (int r = 0; r < 4; ++r) {
                const int rt = w * 4 + r;
                af[r] = *reinterpret_cast<const bf16x8*>(
                            ws + (size_t)((rt * 3 + ks) * 64 + lane) * 8);
            }
            #pragma unroll
            for (int mt = 0; mt < 4; ++mt)
                bfr[mt] = *reinterpret_cast<const bf16x8*>(
                            comb + (size_t)(p0 + mt * 16 + l15) * KP + ks * 32 + l4 * 8);
            #pragma unroll
            for (int r = 0; r < 4; ++r)
                #pragma unroll
                for (int mt = 0; mt < 4; ++mt)
                    acc1[r][mt] = __builtin_amdgcn_mfma_f32_16x16x32_bf16(
                                      af[r], bfr[mt], acc1[r][mt], 0, 0, 0);
        }

        // bias + relu + store h to LDS transposed back: hbuf[m][hid]
        #pragma unroll
        for (int r = 0; r < 4; ++r) {
            const int hid0 = (w * 4 + r) * 16 + l4 * 4;
            const float4 bv = *reinterpret_cast<const float4*>(b1 + hid0);
            #pragma unroll
            for (int mt = 0; mt < 4; ++mt) {
                const int m = mt * 16 + l15;
                ushort4 hv;
                hv.x = f2b(fmaxf(acc1[r][mt][0] + bv.x, 0.f));
                hv.y = f2b(fmaxf(acc1[r][mt][1] + bv.y, 0.f));
                hv.z = f2b(fmaxf(acc1[r][mt][2] + bv.z, 0.f));
                hv.w = f2b(fmaxf(acc1[r][mt][3] + bv.w, 0.f));
                *reinterpret_cast<ushort4*>(&hbuf[m * HSTR + hid0]) = hv;
            }
        }
    }
    __syncthreads();

    // ---- GEMM2: out = h @ W2 + b2 ----
    {
        f32x4 acc2[4][4];                       // [mt(pt)][c(out-tile)]
        #pragma unroll
        for (int mt = 0; mt < 4; ++mt)
            #pragma unroll
            for (int c = 0; c < 4; ++c) acc2[mt][c] = (f32x4)0.f;

        #pragma unroll
        for (int ks = 0; ks < 8; ++ks) {
            bf16x8 af[4], bfr[4];
            #pragma unroll
            for (int mt = 0; mt < 4; ++mt)
                af[mt] = *reinterpret_cast<const bf16x8*>(
                            &hbuf[(mt * 16 + l15) * HSTR + ks * 32 + l4 * 8]);
            #pragma unroll
            for (int c = 0; c < 4; ++c) {
                const int ct = w * 4 + c;
                bfr[c] = *reinterpret_cast<const bf16x8*>(
                            ws + (size_t)(WSA1_N + ((ct * 8 + ks) * 64 + lane) * 8));
            }
            #pragma unroll
            for (int mt = 0; mt < 4; ++mt)
                #pragma unroll
                for (int c = 0; c < 4; ++c)
                    acc2[mt][c] = __builtin_amdgcn_mfma_f32_16x16x32_bf16(
                                      af[mt], bfr[c], acc2[mt][c], 0, 0, 0);
        }

        // epilogue: out[p][col]
        #pragma unroll
        for (int c = 0; c < 4; ++c) {
            const int ct  = w * 4 + c;
            const int col = ct * 16 + l15;
            const float bb = b2[col];
            #pragma unroll
            for (int mt = 0; mt < 4; ++mt) {
                const int ploc = p0 + mt * 16 + l4 * 4;
                #pragma unroll
                for (int r = 0; r < 4; ++r) {
                    const int p = ploc + r;
                    if (p < kPts)
                        out[(size_t)p * kOut + col] = acc2[mt][c][r] + bb;
                }
            }
        }
    }
}

// ---------------- fallback: R2 fused MFMA kernel (proven) ----------------
constexpr int FNBLK = (kMesh + MP - 1) / MP;    // 641
constexpr int CSTR  = 104;

__global__ __launch_bounds__(256)
void g2m_mfma(const float* __restrict__ grid,
              const float* __restrict__ mfeat,
              const int*   __restrict__ indices,
              const float* __restrict__ weights,
              const float* __restrict__ b1,
              const float* __restrict__ b2,
              const ushort* __restrict__ ws,
              float* __restrict__ out)
{
    __shared__ __align__(16) ushort comb[MP * CSTR];
    __shared__ __align__(16) ushort hbuf[MP * HSTR];

    const int t    = threadIdx.x;
    const int lane = t & 63;
    const int w    = t >> 6;
    const int b    = blockIdx.y;
    const int m0   = blockIdx.x * MP;
    const int l15  = lane & 15;
    const int l4   = lane >> 4;

    {
        const int c = lane;
        const float* gb = grid + (size_t)b * (size_t)(kNPix * kCIn);
        #pragma unroll 4
        for (int pass = 0; pass < MP / 4; ++pass) {
            const int p = pass * 4 + w;
            const int m = m0 + p;
            float v = 0.f, mf = 0.f;
            if (m < kMesh) {
                const int4   id = *reinterpret_cast<const int4*>(indices + (size_t)m * 4);
                const float4 wt = *reinterpret_cast<const float4*>(weights + (size_t)m * 4);
                v = fmaf(wt.x, gb[(size_t)id.x * kCIn + c],
                    fmaf(wt.y, gb[(size_t)id.y * kCIn + c],
                    fmaf(wt.z, gb[(size_t)id.z * kCIn + c],
                         wt.w * gb[(size_t)id.w * kCIn + c])));
                if (c < kFeat) mf = mfeat[(size_t)m * kFeat + c];
            }
            comb[p * CSTR + c] = f2b(v);
            if (c < kFeat) comb[p * CSTR + kCIn + c] = f2b(mf);
            if (c < CSTR - kDIn) comb[p * CSTR + kDIn + c] = 0;
        }
    }
    __syncthreads();

    {
        f32x4 acc1[4][4];
        #pragma unroll
        for (int r = 0; r < 4; ++r)
            #pragma unroll
            for (int mt = 0; mt < 4; ++mt) acc1[r][mt] = (f32x4)0.f;

        #pragma unroll
        for (int ks = 0; ks < 3; ++ks) {
            bf16x8 af[4], bfr[4];
            #pragma unroll
            for (int r = 0; r < 4; ++r) {
                const int rt = w * 4 + r;
                af[r] = *reinterpret_cast<const bf16x8*>(
                            ws + (size_t)((rt * 3 + ks) * 64 + lane) * 8);
            }
            #pragma unroll
            for (int mt = 0; mt < 4; ++mt)
                bfr[mt] = *reinterpret_cast<const bf16x8*>(
                            &comb[(mt * 16 + l15) * CSTR + ks * 32 + l4 * 8]);
            #pragma unroll
            for (int r = 0; r < 4; ++r)
                #pragma unroll
                for (int mt = 0; mt < 4; ++mt)
                    acc1[r][mt] = __builtin_amdgcn_mfma_f32_16x16x32_bf16(
                                      af[r], bfr[mt], acc1[r][mt], 0, 0, 0);
        }

        #pragma unroll
        for (int r = 0; r < 4; ++r) {
            const int hid0 = (w * 4 + r) * 16 + l4 * 4;
            const float4 bv = *reinterpret_cast<const float4*>(b1 + hid0);
            #pragma unroll
            for (int mt = 0; mt < 4; ++mt) {
                const int m = mt * 16 + l15;
                ushort4 hv;
                hv.x = f2b(fmaxf(acc1[r][mt][0] + bv.x, 0.f));
                hv.y = f2b(fmaxf(acc1[r][mt][1] + bv.y, 0.f));
                hv.z = f2b(fmaxf(acc1[r][mt][2] + bv.z, 0.f));
                hv.w = f2b(fmaxf(acc1[r][mt][3] + bv.w, 0.f));
                *reinterpret_cast<ushort4*>(&hbuf[m * HSTR + hid0]) = hv;
            }
        }
    }
    __syncthreads();

    {
        f32x4 acc2[4][4];
        #pragma unroll
        for (int mt = 0; mt < 4; ++mt)
            #pragma unroll
            for (int c = 0; c < 4; ++c) acc2[mt][c] = (f32x4)0.f;

        #pragma unroll
        for (int ks = 0; ks < 8; ++ks) {
            bf16x8 af[4], bfr[4];
            #pragma unroll
            for (int mt = 0; mt < 4; ++mt)
                af[mt] = *reinterpret_cast<const bf16x8*>(
                            &hbuf[(mt * 16 + l15) * HSTR + ks * 32 + l4 * 8]);
            #pragma unroll
            for (int c = 0; c < 4; ++c) {
                const int ct = w * 4 + c;
                bfr[c] = *reinterpret_cast<const bf16x8*>(
                            ws + (size_t)(WSA1_N + ((ct * 8 + ks) * 64 + lane) * 8));
            }
            #pragma unroll
            for (int mt = 0; mt < 4; ++mt)
                #pragma unroll
                for (int c = 0; c < 4; ++c)
                    acc2[mt][c] = __builtin_amdgcn_mfma_f32_16x16x32_bf16(
                                      af[mt], bfr[c], acc2[mt][c], 0, 0, 0);
        }

        #pragma unroll
        for (int c = 0; c < 4; ++c) {
            const int ct  = w * 4 + c;
            const int col = ct * 16 + l15;
            const float bb = b2[col];
            #pragma unroll
            for (int mt = 0; mt < 4; ++mt) {
                const int mloc = mt * 16 + l4 * 4;
                #pragma unroll
                for (int r = 0; r < 4; ++r) {
                    const int m = m0 + mloc + r;
                    if (m < kMesh)
                        out[((size_t)b * kMesh + m) * kOut + col] = acc2[mt][c][r] + bb;
                }
            }
        }
    }
}

extern "C" void kernel_launch(void* const* d_in, const int* in_sizes, int n_in,
                              void* d_out, int out_size, void* d_ws, size_t ws_size,
                              hipStream_t stream) {
    const float* grid    = (const float*)d_in[0];
    const float* mfeat   = (const float*)d_in[1];
    const int*   indices = (const int*)d_in[2];
    const float* weights = (const float*)d_in[3];
    const float* W1      = (const float*)d_in[4];
    const float* b1      = (const float*)d_in[5];
    const float* W2      = (const float*)d_in[6];
    const float* b2      = (const float*)d_in[7];
    float* o = (float*)d_out;

    if (ws_size >= WS_SPLIT_BYTES) {
        ushort* ws   = (ushort*)d_ws;
        ushort* comb = ws + COMB_OFF;
        g2m_prep<<<44, 256, 0, stream>>>(W1, W2, ws);
        g2m_gather<<<2048, 256, 0, stream>>>(grid, mfeat, indices, weights, comb);
        g2m_mlp<<<NBLKB, 256, 0, stream>>>(comb, b1, b2, ws, o);
    } else if (ws_size >= WS_FUSED_BYTES) {
        ushort* ws = (ushort*)d_ws;
        g2m_prep<<<44, 256, 0, stream>>>(W1, W2, ws);
        dim3 grd(FNBLK, kBatch);
        g2m_mfma<<<grd, 256, 0, stream>>>(grid, mfeat, indices, weights, b1, b2, ws, o);
    }
}

// Round 4
// 54.309 us; speedup vs baseline: 3.3730x; 1.1477x over previous
//
#include <hip/hip_runtime.h>
#include <hip/hip_bf16.h>

// GridToMeshEncoder R4:
//   g2m_gather : prep (folded) + 4-pts/wave vectorized gather -> bf16 comb[p][96]
//   g2m_mlp    : GEMM1 (h^T = W1^T*comb^T) -> LDS -> GEMM2 transposed
//                (out^T = W2^T*h^T, float4 epilogue stores)
// Fallback: R2 fused MFMA kernel if ws too small for comb.

constexpr int kNLat  = 721;
constexpr int kNLon  = 1440;
constexpr long long kNPix = (long long)kNLat * kNLon;   // 1038240
constexpr int kMesh  = 40962;
constexpr int kCIn   = 64;
constexpr int kFeat  = 4;
constexpr int kDIn   = kCIn + kFeat;                    // 68
constexpr int kHid   = 256;
constexpr int kOut   = 256;
constexpr int kBatch = 2;

constexpr int kPts    = kBatch * kMesh;                 // 81924
constexpr int kPtsPad = (kPts + 63) & ~63;              // 81984
constexpr int KP      = 96;                             // padded K for comb

typedef __attribute__((ext_vector_type(8))) short bf16x8;
typedef __attribute__((ext_vector_type(4))) float f32x4;

// ws layout (ushort units)
constexpr int    WSA1_N   = 16 * 3 * 64 * 8;            // 24576  (W1^T A-frags)
constexpr int    WSB2_N   = 16 * 8 * 64 * 8;            // 65536  (W2 B/A'-frags)
constexpr size_t COMB_OFF = WSA1_N + WSB2_N;            // 90112
constexpr size_t COMB_N   = (size_t)kPtsPad * KP;
constexpr size_t WS_SPLIT_BYTES = (COMB_OFF + COMB_N) * 2;
constexpr size_t WS_FUSED_BYTES = COMB_OFF * 2;

__device__ inline ushort f2b(float v) {
    __hip_bfloat16 h = __float2bfloat16(v);
    return *reinterpret_cast<ushort*>(&h);
}

// ---------------- prep body: pack W1/W2 into frag-ordered bf16 ----------------
__device__ inline void prep_body(int tid, const float* __restrict__ W1,
                                 const float* __restrict__ W2,
                                 ushort* __restrict__ ws) {
    if (tid < 3072) {                       // wsA1: A[i=hid][k] = W1[k][hid]
        const int l  = tid & 63;
        const int g  = tid >> 6;            // g = rt*3 + ks
        const int ks = g % 3;
        const int rt = g / 3;
        const int hid = rt * 16 + (l & 15);
        const int k0  = ks * 32 + (l >> 4) * 8;
        ushort tmp[8];
        #pragma unroll
        for (int j = 0; j < 8; ++j) {
            const int k = k0 + j;
            tmp[j] = f2b(k < kDIn ? W1[(size_t)k * kHid + hid] : 0.f);
        }
        *reinterpret_cast<bf16x8*>(ws + (size_t)tid * 8) =
            *reinterpret_cast<bf16x8*>(tmp);
    } else if (tid < 11264) {               // wsB2: [ct][ks][lane][8] = W2[k][col]
        const int q  = tid - 3072;
        const int l  = q & 63;
        const int g  = q >> 6;              // g = ct*8 + ks
        const int ks = g % 8;
        const int ct = g / 8;
        const int col = ct * 16 + (l & 15);
        const int k0  = ks * 32 + (l >> 4) * 8;
        ushort tmp[8];
        #pragma unroll
        for (int j = 0; j < 8; ++j) {
            const int k = k0 + j;
            tmp[j] = f2b(W2[(size_t)k * kOut + col]);
        }
        *reinterpret_cast<bf16x8*>(ws + (size_t)(WSA1_N + q * 8)) =
            *reinterpret_cast<bf16x8*>(tmp);
    }
}

__global__ __launch_bounds__(256)
void g2m_prep(const float* __restrict__ W1, const float* __restrict__ W2,
              ushort* __restrict__ ws) {
    prep_body(blockIdx.x * 256 + threadIdx.x, W1, W2, ws);
}

// ---------------- gather v2: 4 points per wave-iteration ----------------
constexpr int NGB = 1708;   // 1708 blocks * 4 waves * 3 iters * 4 pts = 81984

__global__ __launch_bounds__(256)
void g2m_gather(const float* __restrict__ grid,
                const float* __restrict__ mfeat,
                const int*   __restrict__ indices,
                const float* __restrict__ weights,
                const float* __restrict__ W1,
                const float* __restrict__ W2,
                ushort* __restrict__ ws) {
    const int tid = blockIdx.x * 256 + threadIdx.x;
    if (tid < 11264) prep_body(tid, W1, W2, ws);   // folded prep

    ushort* comb = ws + COMB_OFF;
    const int lane = threadIdx.x & 63;
    const int l15  = lane & 15;            // channel quad
    const int q    = lane >> 4;            // point-in-group 0..3
    const int wid  = tid >> 6;
    const int nw   = NGB * 4;

    #pragma unroll
    for (int it = 0; it < 3; ++it) {
        const int g = wid + it * nw;       // point group
        const int p = g * 4 + q;           // this lane's point
        float4 acc = {0.f, 0.f, 0.f, 0.f};
        float mf0 = 0.f, mf1 = 0.f;
        if (p < kPts) {
            const int b = (p >= kMesh) ? 1 : 0;
            const int m = p - b * kMesh;
            const int4   id = *reinterpret_cast<const int4*>(indices + (size_t)m * 4);
            const float4 wt = *reinterpret_cast<const float4*>(weights + (size_t)m * 4);
            const float* gb = grid + (size_t)b * (size_t)(kNPix * kCIn);
            const float4 r0 = *reinterpret_cast<const float4*>(gb + (size_t)id.x * kCIn + l15 * 4);
            const float4 r1 = *reinterpret_cast<const float4*>(gb + (size_t)id.y * kCIn + l15 * 4);
            const float4 r2 = *reinterpret_cast<const float4*>(gb + (size_t)id.z * kCIn + l15 * 4);
            const float4 r3 = *reinterpret_cast<const float4*>(gb + (size_t)id.w * kCIn + l15 * 4);
            acc.x = fmaf(wt.x, r0.x, fmaf(wt.y, r1.x, fmaf(wt.z, r2.x, wt.w * r3.x)));
            acc.y = fmaf(wt.x, r0.y, fmaf(wt.y, r1.y, fmaf(wt.z, r2.y, wt.w * r3.y)));
            acc.z = fmaf(wt.x, r0.z, fmaf(wt.y, r1.z, fmaf(wt.z, r2.z, wt.w * r3.z)));
            acc.w = fmaf(wt.x, r0.w, fmaf(wt.y, r1.w, fmaf(wt.z, r2.w, wt.w * r3.w)));
            if (l15 < 2) {
                mf0 = mfeat[(size_t)m * kFeat + l15 * 2];
                mf1 = mfeat[(size_t)m * kFeat + l15 * 2 + 1];
            }
        }
        ushort* row = comb + (size_t)p * KP;
        ushort4 pk;
        pk.x = f2b(acc.x); pk.y = f2b(acc.y); pk.z = f2b(acc.z); pk.w = f2b(acc.w);
        *reinterpret_cast<ushort4*>(row + l15 * 4) = pk;      // cols 0..63
        ushort2 ft;                                            // cols 64..95
        ft.x = f2b(mf0); ft.y = f2b(mf1);
        *reinterpret_cast<ushort2*>(row + 64 + l15 * 2) = ft;
    }
}

// ---------------- MLP: GEMM1 -> LDS -> GEMM2^T -> out ----------------
constexpr int MP    = 64;                       // points per block
constexpr int NBLKB = kPtsPad / MP;             // 1281
constexpr int HSTR  = 264;                      // hbuf row stride (bf16)

__global__ __launch_bounds__(256)
void g2m_mlp(const ushort* __restrict__ comb,
             const float* __restrict__ b1,
             const float* __restrict__ b2,
             const ushort* __restrict__ ws,
             float* __restrict__ out)
{
    __shared__ __align__(16) ushort hbuf[MP * HSTR];    // 33792 B

    const int t    = threadIdx.x;
    const int lane = t & 63;
    const int w    = t >> 6;                    // wave id 0..3
    const int p0   = blockIdx.x * MP;
    const int l15  = lane & 15;
    const int l4   = lane >> 4;

    // ---- GEMM1: h^T = W1^T @ comb^T ----
    {
        f32x4 acc1[4][4];                       // [r(hid-tile)][mt(pt-tile)]
        #pragma unroll
        for (int r = 0; r < 4; ++r)
            #pragma unroll
            for (int mt = 0; mt < 4; ++mt) acc1[r][mt] = (f32x4)0.f;

        #pragma unroll
        for (int ks = 0; ks < 3; ++ks) {
            bf16x8 af[4], bfr[4];
            #pragma unroll
            for (int r = 0; r < 4; ++r) {
                const int rt = w * 4 + r;
                af[r] = *reinterpret_cast<const bf16x8*>(
                            ws + (size_t)((rt * 3 + ks) * 64 + lane) * 8);
            }
            #pragma unroll
            for (int mt = 0; mt < 4; ++mt)
                bfr[mt] = *reinterpret_cast<const bf16x8*>(
                            comb + (size_t)(p0 + mt * 16 + l15) * KP + ks * 32 + l4 * 8);
            #pragma unroll
            for (int r = 0; r < 4; ++r)
                #pragma unroll
                for (int mt = 0; mt < 4; ++mt)
                    acc1[r][mt] = __builtin_amdgcn_mfma_f32_16x16x32_bf16(
                                      af[r], bfr[mt], acc1[r][mt], 0, 0, 0);
        }

        // bias + relu + store h to LDS: hbuf[m][hid]
        #pragma unroll
        for (int r = 0; r < 4; ++r) {
            const int hid0 = (w * 4 + r) * 16 + l4 * 4;
            const float4 bv = *reinterpret_cast<const float4*>(b1 + hid0);
            #pragma unroll
            for (int mt = 0; mt < 4; ++mt) {
                const int m = mt * 16 + l15;
                ushort4 hv;
                hv.x = f2b(fmaxf(acc1[r][mt][0] + bv.x, 0.f));
                hv.y = f2b(fmaxf(acc1[r][mt][1] + bv.y, 0.f));
                hv.z = f2b(fmaxf(acc1[r][mt][2] + bv.z, 0.f));
                hv.w = f2b(fmaxf(acc1[r][mt][3] + bv.w, 0.f));
                *reinterpret_cast<ushort4*>(&hbuf[m * HSTR + hid0]) = hv;
            }
        }
    }
    __syncthreads();

    // ---- GEMM2 transposed: out^T = W2^T @ h^T ----
    {
        f32x4 acc2[4][4];                       // [mt(pt-tile)][c(outcol-tile)]
        #pragma unroll
        for (int mt = 0; mt < 4; ++mt)
            #pragma unroll
            for (int c = 0; c < 4; ++c) acc2[mt][c] = (f32x4)0.f;

        #pragma unroll
        for (int ks = 0; ks < 8; ++ks) {
            bf16x8 hf[4], wf[4];
            #pragma unroll
            for (int mt = 0; mt < 4; ++mt)
                hf[mt] = *reinterpret_cast<const bf16x8*>(
                            &hbuf[(mt * 16 + l15) * HSTR + ks * 32 + l4 * 8]);
            #pragma unroll
            for (int c = 0; c < 4; ++c) {
                const int ct = w * 4 + c;
                wf[c] = *reinterpret_cast<const bf16x8*>(
                            ws + (size_t)(WSA1_N + ((ct * 8 + ks) * 64 + lane) * 8));
            }
            // A = W2^T frag (wsB2 packing), B = h^T frag (hbuf read)
            #pragma unroll
            for (int mt = 0; mt < 4; ++mt)
                #pragma unroll
                for (int c = 0; c < 4; ++c)
                    acc2[mt][c] = __builtin_amdgcn_mfma_f32_16x16x32_bf16(
                                      wf[c], hf[mt], acc2[mt][c], 0, 0, 0);
        }

        // epilogue: lane holds 4 consecutive out cols for one point -> float4
        #pragma unroll
        for (int c = 0; c < 4; ++c) {
            const int col0 = (w * 4 + c) * 16 + l4 * 4;
            const float4 bv = *reinterpret_cast<const float4*>(b2 + col0);
            #pragma unroll
            for (int mt = 0; mt < 4; ++mt) {
                const int p = p0 + mt * 16 + l15;
                if (p < kPts) {
                    float4 o;
                    o.x = acc2[mt][c][0] + bv.x;
                    o.y = acc2[mt][c][1] + bv.y;
                    o.z = acc2[mt][c][2] + bv.z;
                    o.w = acc2[mt][c][3] + bv.w;
                    *reinterpret_cast<float4*>(out + (size_t)p * kOut + col0) = o;
                }
            }
        }
    }
}

// ---------------- fallback: R2 fused MFMA kernel (proven) ----------------
constexpr int FNBLK = (kMesh + MP - 1) / MP;    // 641
constexpr int CSTR  = 104;

__global__ __launch_bounds__(256)
void g2m_mfma(const float* __restrict__ grid,
              const float* __restrict__ mfeat,
              const int*   __restrict__ indices,
              const float* __restrict__ weights,
              const float* __restrict__ b1,
              const float* __restrict__ b2,
              const ushort* __restrict__ ws,
              float* __restrict__ out)
{
    __shared__ __align__(16) ushort comb[MP * CSTR];
    __shared__ __align__(16) ushort hbuf[MP * HSTR];

    const int t    = threadIdx.x;
    const int lane = t & 63;
    const int w    = t >> 6;
    const int b    = blockIdx.y;
    const int m0   = blockIdx.x * MP;
    const int l15  = lane & 15;
    const int l4   = lane >> 4;

    {
        const int c = lane;
        const float* gb = grid + (size_t)b * (size_t)(kNPix * kCIn);
        #pragma unroll 4
        for (int pass = 0; pass < MP / 4; ++pass) {
            const int p = pass * 4 + w;
            const int m = m0 + p;
            float v = 0.f, mf = 0.f;
            if (m < kMesh) {
                const int4   id = *reinterpret_cast<const int4*>(indices + (size_t)m * 4);
                const float4 wt = *reinterpret_cast<const float4*>(weights + (size_t)m * 4);
                v = fmaf(wt.x, gb[(size_t)id.x * kCIn + c],
                    fmaf(wt.y, gb[(size_t)id.y * kCIn + c],
                    fmaf(wt.z, gb[(size_t)id.z * kCIn + c],
                         wt.w * gb[(size_t)id.w * kCIn + c])));
                if (c < kFeat) mf = mfeat[(size_t)m * kFeat + c];
            }
            comb[p * CSTR + c] = f2b(v);
            if (c < kFeat) comb[p * CSTR + kCIn + c] = f2b(mf);
            if (c < CSTR - kDIn) comb[p * CSTR + kDIn + c] = 0;
        }
    }
    __syncthreads();

    {
        f32x4 acc1[4][4];
        #pragma unroll
        for (int r = 0; r < 4; ++r)
            #pragma unroll
            for (int mt = 0; mt < 4; ++mt) acc1[r][mt] = (f32x4)0.f;

        #pragma unroll
        for (int ks = 0; ks < 3; ++ks) {
            bf16x8 af[4], bfr[4];
            #pragma unroll
            for (int r = 0; r < 4; ++r) {
                const int rt = w * 4 + r;
                af[r] = *reinterpret_cast<const bf16x8*>(
                            ws + (size_t)((rt * 3 + ks) * 64 + lane) * 8);
            }
            #pragma unroll
            for (int mt = 0; mt < 4; ++mt)
                bfr[mt] = *reinterpret_cast<const bf16x8*>(
                            &comb[(mt * 16 + l15) * CSTR + ks * 32 + l4 * 8]);
            #pragma unroll
            for (int r = 0; r < 4; ++r)
                #pragma unroll
                for (int mt = 0; mt < 4; ++mt)
                    acc1[r][mt] = __builtin_amdgcn_mfma_f32_16x16x32_bf16(
                                      af[r], bfr[mt], acc1[r][mt], 0, 0, 0);
        }

        #pragma unroll
        for (int r = 0; r < 4; ++r) {
            const int hid0 = (w * 4 + r) * 16 + l4 * 4;
            const float4 bv = *reinterpret_cast<const float4*>(b1 + hid0);
            #pragma unroll
            for (int mt = 0; mt < 4; ++mt) {
                const int m = mt * 16 + l15;
                ushort4 hv;
                hv.x = f2b(fmaxf(acc1[r][mt][0] + bv.x, 0.f));
                hv.y = f2b(fmaxf(acc1[r][mt][1] + bv.y, 0.f));
                hv.z = f2b(fmaxf(acc1[r][mt][2] + bv.z, 0.f));
                hv.w = f2b(fmaxf(acc1[r][mt][3] + bv.w, 0.f));
                *reinterpret_cast<ushort4*>(&hbuf[m * HSTR + hid0]) = hv;
            }
        }
    }
    __syncthreads();

    {
        f32x4 acc2[4][4];
        #pragma unroll
        for (int mt = 0; mt < 4; ++mt)
            #pragma unroll
            for (int c = 0; c < 4; ++c) acc2[mt][c] = (f32x4)0.f;

        #pragma unroll
        for (int ks = 0; ks < 8; ++ks) {
            bf16x8 af[4], bfr[4];
            #pragma unroll
            for (int mt = 0; mt < 4; ++mt)
                af[mt] = *reinterpret_cast<const bf16x8*>(
                            &hbuf[(mt * 16 + l15) * HSTR + ks * 32 + l4 * 8]);
            #pragma unroll
            for (int c = 0; c < 4; ++c) {
                const int ct = w * 4 + c;
                bfr[c] = *reinterpret_cast<const bf16x8*>(
                            ws + (size_t)(WSA1_N + ((ct * 8 + ks) * 64 + lane) * 8));
            }
            #pragma unroll
            for (int mt = 0; mt < 4; ++mt)
                #pragma unroll
                for (int c = 0; c < 4; ++c)
                    acc2[mt][c] = __builtin_amdgcn_mfma_f32_16x16x32_bf16(
                                      af[mt], bfr[c], acc2[mt][c], 0, 0, 0);
        }

        #pragma unroll
        for (int c = 0; c < 4; ++c) {
            const int ct  = w * 4 + c;
            const int col = ct * 16 + l15;
            const float bb = b2[col];
            #pragma unroll
            for (int mt = 0; mt < 4; ++mt) {
                const int mloc = mt * 16 + l4 * 4;
                #pragma unroll
                for (int r = 0; r < 4; ++r) {
                    const int m = m0 + mloc + r;
                    if (m < kMesh)
                        out[((size_t)b * kMesh + m) * kOut + col] = acc2[mt][c][r] + bb;
                }
            }
        }
    }
}

extern "C" void kernel_launch(void* const* d_in, const int* in_sizes, int n_in,
                              void* d_out, int out_size, void* d_ws, size_t ws_size,
                              hipStream_t stream) {
    const float* grid    = (const float*)d_in[0];
    const float* mfeat   = (const float*)d_in[1];
    const int*   indices = (const int*)d_in[2];
    const float* weights = (const float*)d_in[3];
    const float* W1      = (const float*)d_in[4];
    const float* b1      = (const float*)d_in[5];
    const float* W2      = (const float*)d_in[6];
    const float* b2      = (const float*)d_in[7];
    float* o = (float*)d_out;

    if (ws_size >= WS_SPLIT_BYTES) {
        ushort* ws   = (ushort*)d_ws;
        ushort* comb = ws + COMB_OFF;
        g2m_gather<<<NGB, 256, 0, stream>>>(grid, mfeat, indices, weights, W1, W2, ws);
        g2m_mlp<<<NBLKB, 256, 0, stream>>>(comb, b1, b2, ws, o);
    } else if (ws_size >= WS_FUSED_BYTES) {
        ushort* ws = (ushort*)d_ws;
        g2m_prep<<<44, 256, 0, stream>>>(W1, W2, ws);
        dim3 grd(FNBLK, kBatch);
        g2m_mfma<<<grd, 256, 0, stream>>>(grid, mfeat, indices, weights, b1, b2, ws, o);
    }
}

// Round 5
// 51.810 us; speedup vs baseline: 3.5357x; 1.0482x over previous
//
#include <hip/hip_runtime.h>
#include <hip/hip_bf16.h>

// GridToMeshEncoder R5: single fused kernel (vectorized gather -> LDS comb ->
// GEMM1 h^T=W1^T*comb^T -> LDS hbuf -> GEMM2^T out^T=W2^T*h^T -> float4 out),
// plus a tiny prep kernel packing W1/W2 into MFMA fragment order (L2-resident).

constexpr int kNLat  = 721;
constexpr int kNLon  = 1440;
constexpr long long kNPix = (long long)kNLat * kNLon;   // 1038240
constexpr int kMesh  = 40962;
constexpr int kCIn   = 64;
constexpr int kFeat  = 4;
constexpr int kDIn   = kCIn + kFeat;                    // 68
constexpr int kHid   = 256;
constexpr int kOut   = 256;
constexpr int kBatch = 2;

constexpr int kPts    = kBatch * kMesh;                 // 81924
constexpr int kPtsPad = (kPts + 63) & ~63;              // 81984

typedef __attribute__((ext_vector_type(8))) short bf16x8;
typedef __attribute__((ext_vector_type(4))) float f32x4;

// ws layout (ushort units): wsA1 = W1^T A-frags [rt:16][ks:3][lane:64][j:8]
//                           wsB2 = W2   frags   [ct:16][ks:8][lane:64][j:8]
constexpr int    WSA1_N   = 16 * 3 * 64 * 8;            // 24576
constexpr int    WSB2_N   = 16 * 8 * 64 * 8;            // 65536
constexpr size_t WS_BYTES = (size_t)(WSA1_N + WSB2_N) * 2;  // 180224

constexpr int MP    = 64;                       // points per block
constexpr int NBLKB = kPtsPad / MP;             // 1281
constexpr int CSTR  = 104;                      // comb row stride (bf16)
constexpr int HSTR  = 264;                      // hbuf row stride (bf16)

__device__ inline ushort f2b(float v) {
    __hip_bfloat16 h = __float2bfloat16(v);
    return *reinterpret_cast<ushort*>(&h);
}

// ---------------- prep: pack W1/W2 into frag-ordered bf16 ----------------
__global__ __launch_bounds__(256)
void g2m_prep(const float* __restrict__ W1, const float* __restrict__ W2,
              ushort* __restrict__ ws) {
    const int tid = blockIdx.x * 256 + threadIdx.x;
    if (tid < 3072) {                       // wsA1: A[i=hid][k] = W1[k][hid]
        const int l  = tid & 63;
        const int g  = tid >> 6;            // g = rt*3 + ks
        const int ks = g % 3;
        const int rt = g / 3;
        const int hid = rt * 16 + (l & 15);
        const int k0  = ks * 32 + (l >> 4) * 8;
        ushort tmp[8];
        #pragma unroll
        for (int j = 0; j < 8; ++j) {
            const int k = k0 + j;
            tmp[j] = f2b(k < kDIn ? W1[(size_t)k * kHid + hid] : 0.f);
        }
        *reinterpret_cast<bf16x8*>(ws + (size_t)tid * 8) =
            *reinterpret_cast<bf16x8*>(tmp);
    } else if (tid < 11264) {               // wsB2: [ct][ks][lane][8] = W2[k][col]
        const int q  = tid - 3072;
        const int l  = q & 63;
        const int g  = q >> 6;              // g = ct*8 + ks
        const int ks = g % 8;
        const int ct = g / 8;
        const int col = ct * 16 + (l & 15);
        const int k0  = ks * 32 + (l >> 4) * 8;
        ushort tmp[8];
        #pragma unroll
        for (int j = 0; j < 8; ++j) {
            const int k = k0 + j;
            tmp[j] = f2b(W2[(size_t)k * kOut + col]);
        }
        *reinterpret_cast<bf16x8*>(ws + (size_t)(WSA1_N + q * 8)) =
            *reinterpret_cast<bf16x8*>(tmp);
    }
}

// ---------------- fused: gather -> GEMM1 -> GEMM2^T -> out ----------------
__global__ __launch_bounds__(256, 3)
void g2m_fused2(const float* __restrict__ grid,
                const float* __restrict__ mfeat,
                const int*   __restrict__ indices,
                const float* __restrict__ weights,
                const float* __restrict__ b1,
                const float* __restrict__ b2,
                const ushort* __restrict__ ws,
                float* __restrict__ out)
{
    __shared__ __align__(16) ushort comb[MP * CSTR];    // 13312 B
    __shared__ __align__(16) ushort hbuf[MP * HSTR];    // 33792 B

    const int t    = threadIdx.x;
    const int lane = t & 63;
    const int w    = t >> 6;                    // wave id 0..3
    const int p0   = blockIdx.x * MP;
    const int l15  = lane & 15;
    const int l4   = lane >> 4;

    // ---- phase 1: vectorized gather, 4 points per wave-iteration ----
    {
        const int q = l4;                       // point-in-group 0..3
        #pragma unroll
        for (int it = 0; it < 4; ++it) {
            const int row = (w * 4 + it) * 4 + q;   // local row 0..63
            const int p   = p0 + row;
            float4 acc = {0.f, 0.f, 0.f, 0.f};
            float mf0 = 0.f, mf1 = 0.f;
            if (p < kPts) {
                const int b = (p >= kMesh) ? 1 : 0;
                const int m = p - b * kMesh;
                const int4   id = *reinterpret_cast<const int4*>(indices + (size_t)m * 4);
                const float4 wt = *reinterpret_cast<const float4*>(weights + (size_t)m * 4);
                const float* gb = grid + (size_t)b * (size_t)(kNPix * kCIn);
                const float4 r0 = *reinterpret_cast<const float4*>(gb + (size_t)id.x * kCIn + l15 * 4);
                const float4 r1 = *reinterpret_cast<const float4*>(gb + (size_t)id.y * kCIn + l15 * 4);
                const float4 r2 = *reinterpret_cast<const float4*>(gb + (size_t)id.z * kCIn + l15 * 4);
                const float4 r3 = *reinterpret_cast<const float4*>(gb + (size_t)id.w * kCIn + l15 * 4);
                acc.x = fmaf(wt.x, r0.x, fmaf(wt.y, r1.x, fmaf(wt.z, r2.x, wt.w * r3.x)));
                acc.y = fmaf(wt.x, r0.y, fmaf(wt.y, r1.y, fmaf(wt.z, r2.y, wt.w * r3.y)));
                acc.z = fmaf(wt.x, r0.z, fmaf(wt.y, r1.z, fmaf(wt.z, r2.z, wt.w * r3.z)));
                acc.w = fmaf(wt.x, r0.w, fmaf(wt.y, r1.w, fmaf(wt.z, r2.w, wt.w * r3.w)));
                if (l15 < 2) {
                    mf0 = mfeat[(size_t)m * kFeat + l15 * 2];
                    mf1 = mfeat[(size_t)m * kFeat + l15 * 2 + 1];
                }
            }
            ushort* rowp = &comb[row * CSTR];
            ushort4 pk;
            pk.x = f2b(acc.x); pk.y = f2b(acc.y); pk.z = f2b(acc.z); pk.w = f2b(acc.w);
            *reinterpret_cast<ushort4*>(rowp + l15 * 4) = pk;       // cols 0..63
            ushort2 ft;                                              // cols 64..95
            ft.x = f2b(mf0); ft.y = f2b(mf1);
            *reinterpret_cast<ushort2*>(rowp + 64 + l15 * 2) = ft;
        }
    }
    __syncthreads();

    // ---- phase 2: GEMM1  h^T = W1^T @ comb^T ----
    {
        f32x4 acc1[4][4];                       // [r(hid-tile)][mt(pt-tile)]
        #pragma unroll
        for (int r = 0; r < 4; ++r)
            #pragma unroll
            for (int mt = 0; mt < 4; ++mt) acc1[r][mt] = (f32x4)0.f;

        #pragma unroll
        for (int ks = 0; ks < 3; ++ks) {
            bf16x8 af[4], bfr[4];
            #pragma unroll
            for (int r = 0; r < 4; ++r) {
                const int rt = w * 4 + r;
                af[r] = *reinterpret_cast<const bf16x8*>(
                            ws + (size_t)((rt * 3 + ks) * 64 + lane) * 8);
            }
            #pragma unroll
            for (int mt = 0; mt < 4; ++mt)
                bfr[mt] = *reinterpret_cast<const bf16x8*>(
                            &comb[(mt * 16 + l15) * CSTR + ks * 32 + l4 * 8]);
            #pragma unroll
            for (int r = 0; r < 4; ++r)
                #pragma unroll
                for (int mt = 0; mt < 4; ++mt)
                    acc1[r][mt] = __builtin_amdgcn_mfma_f32_16x16x32_bf16(
                                      af[r], bfr[mt], acc1[r][mt], 0, 0, 0);
        }

        // bias + relu -> hbuf[m][hid] (bf16)
        #pragma unroll
        for (int r = 0; r < 4; ++r) {
            const int hid0 = (w * 4 + r) * 16 + l4 * 4;
            const float4 bv = *reinterpret_cast<const float4*>(b1 + hid0);
            #pragma unroll
            for (int mt = 0; mt < 4; ++mt) {
                const int m = mt * 16 + l15;
                ushort4 hv;
                hv.x = f2b(fmaxf(acc1[r][mt][0] + bv.x, 0.f));
                hv.y = f2b(fmaxf(acc1[r][mt][1] + bv.y, 0.f));
                hv.z = f2b(fmaxf(acc1[r][mt][2] + bv.z, 0.f));
                hv.w = f2b(fmaxf(acc1[r][mt][3] + bv.w, 0.f));
                *reinterpret_cast<ushort4*>(&hbuf[m * HSTR + hid0]) = hv;
            }
        }
    }
    __syncthreads();

    // ---- phase 3: GEMM2 transposed  out^T = W2^T @ h^T ----
    {
        f32x4 acc2[4][4];                       // [mt(pt-tile)][c(outcol-tile)]
        #pragma unroll
        for (int mt = 0; mt < 4; ++mt)
            #pragma unroll
            for (int c = 0; c < 4; ++c) acc2[mt][c] = (f32x4)0.f;

        #pragma unroll
        for (int ks = 0; ks < 8; ++ks) {
            bf16x8 hf[4], wf[4];
            #pragma unroll
            for (int mt = 0; mt < 4; ++mt)
                hf[mt] = *reinterpret_cast<const bf16x8*>(
                            &hbuf[(mt * 16 + l15) * HSTR + ks * 32 + l4 * 8]);
            #pragma unroll
            for (int c = 0; c < 4; ++c) {
                const int ct = w * 4 + c;
                wf[c] = *reinterpret_cast<const bf16x8*>(
                            ws + (size_t)(WSA1_N + ((ct * 8 + ks) * 64 + lane) * 8));
            }
            #pragma unroll
            for (int mt = 0; mt < 4; ++mt)
                #pragma unroll
                for (int c = 0; c < 4; ++c)
                    acc2[mt][c] = __builtin_amdgcn_mfma_f32_16x16x32_bf16(
                                      wf[c], hf[mt], acc2[mt][c], 0, 0, 0);
        }

        // epilogue: lane holds 4 consecutive out cols for one point -> float4
        #pragma unroll
        for (int c = 0; c < 4; ++c) {
            const int col0 = (w * 4 + c) * 16 + l4 * 4;
            const float4 bv = *reinterpret_cast<const float4*>(b2 + col0);
            #pragma unroll
            for (int mt = 0; mt < 4; ++mt) {
                const int p = p0 + mt * 16 + l15;
                if (p < kPts) {
                    float4 o;
                    o.x = acc2[mt][c][0] + bv.x;
                    o.y = acc2[mt][c][1] + bv.y;
                    o.z = acc2[mt][c][2] + bv.z;
                    o.w = acc2[mt][c][3] + bv.w;
                    *reinterpret_cast<float4*>(out + (size_t)p * kOut + col0) = o;
                }
            }
        }
    }
}

extern "C" void kernel_launch(void* const* d_in, const int* in_sizes, int n_in,
                              void* d_out, int out_size, void* d_ws, size_t ws_size,
                              hipStream_t stream) {
    const float* grid    = (const float*)d_in[0];
    const float* mfeat   = (const float*)d_in[1];
    const int*   indices = (const int*)d_in[2];
    const float* weights = (const float*)d_in[3];
    const float* W1      = (const float*)d_in[4];
    const float* b1      = (const float*)d_in[5];
    const float* W2      = (const float*)d_in[6];
    const float* b2      = (const float*)d_in[7];
    float* o = (float*)d_out;

    if (ws_size >= WS_BYTES) {
        ushort* ws = (ushort*)d_ws;
        g2m_prep<<<44, 256, 0, stream>>>(W1, W2, ws);
        g2m_fused2<<<NBLKB, 256, 0, stream>>>(grid, mfeat, indices, weights,
                                              b1, b2, ws, o);
    }
}